// Round 7
// baseline (79.568 us; speedup 1.0000x reference)
//
#include <hip/hip_runtime.h>

// Problem constants (from reference): B=4096, V=64 (variables), F=128 (factors), HO=3
constexpr int Bn  = 4096;
constexpr int Vn  = 64;
constexpr int Fn  = 128;
constexpr int NPB = Vn * Fn;   // 8192 elements per batch slice

typedef float f32x4 __attribute__((ext_vector_type(4)));
typedef unsigned long long u64;

// Branchless insert of key k into descending triple (m0 >= m1 >= m2).
// Key = (float_bits << 6) | (63 ^ row): value desc, row asc on ties (= stable
// top_k; keys are unique so merges in any order give the global top-3).
__device__ __forceinline__ void kins(u64 k, u64& m0, u64& m1, u64& m2) {
    const u64 a = m0 > k ? m0 : k;
    const u64 b = m0 > k ? k  : m0;
    m0 = a;
    const u64 c = m1 > b ? m1 : b;
    const u64 d = m1 > b ? b  : m1;
    m1 = c;
    m2 = m2 > d ? m2 : d;
}

// ONE WAVE PER BATCH. Lane l, iter i reads element l + 64*i of the 8192-slice:
//   col = (4*l) & 127   -- constant per lane across all 32 iters
//   row = (l>>5) + 2*i  -- lanes 0-31 even rows, 32-63 odd rows
// Lanes l and l^32 share columns and jointly cover all 64 rows, so the full
// per-column top-3 is: 32 in-register kins + ONE shfl_xor(32) merge.
// Zero LDS, zero __syncthreads, 4 fully independent waves per block.
__global__ __launch_bounds__(256)
void adj_generator_kernel(const float* __restrict__ sm_g,
                          float* __restrict__ out_sm,
                          float* __restrict__ out_adj,
                          float* __restrict__ out_ent) {
    const int wv = threadIdx.x >> 6;           // wave within block
    const int l  = threadIdx.x & 63;           // lane
    const int b  = blockIdx.x * 4 + wv;        // batch handled by this wave

    const f32x4* s4 = (const f32x4*)(sm_g   + (size_t)b * NPB);
    f32x4*       o4 = (f32x4*)(out_sm + (size_t)b * NPB);

    u64 m0[4], m1[4], m2[4];
    #pragma unroll
    for (int c = 0; c < 4; ++c) { m0[c] = 0; m1[c] = 0; m2[c] = 0; }

    unsigned int pr[4] = {0u, 0u, 0u, 0u};     // (x > 0.01) bit per iter, per col
    float esum = 0.0f;
    const int rbase = l >> 5;                  // 0 (even rows) or 1 (odd rows)

    // ---- Single streaming pass: load + NT copy + entropy + pred + top-3 ----
    #pragma unroll 8
    for (int i = 0; i < 32; ++i) {
        const int idx = l + 64 * i;
        const f32x4 v = __builtin_nontemporal_load(&s4[idx]);
        __builtin_nontemporal_store(v, &o4[idx]);   // softmax pass-through
        esum -= v.x * __logf(v.x) + v.y * __logf(v.y)
              + v.z * __logf(v.z) + v.w * __logf(v.w);
        pr[0] |= (v.x > 0.01f ? 1u : 0u) << i;
        pr[1] |= (v.y > 0.01f ? 1u : 0u) << i;
        pr[2] |= (v.z > 0.01f ? 1u : 0u) << i;
        pr[3] |= (v.w > 0.01f ? 1u : 0u) << i;
        const u64 rk = (u64)(63 ^ (rbase + 2 * i));
        kins(((u64)__float_as_uint(v.x) << 6) | rk, m0[0], m1[0], m2[0]);
        kins(((u64)__float_as_uint(v.y) << 6) | rk, m0[1], m1[1], m2[1]);
        kins(((u64)__float_as_uint(v.z) << 6) | rk, m0[2], m1[2], m2[2]);
        kins(((u64)__float_as_uint(v.w) << 6) | rk, m0[3], m1[3], m2[3]);
    }

    // ---- Pair-merge: lane l <-> l^32 (same cols, complementary rows) ----
    #pragma unroll
    for (int c = 0; c < 4; ++c) {
        const u64 p0 = (u64)__shfl_xor((long long)m0[c], 32);
        const u64 p1 = (u64)__shfl_xor((long long)m1[c], 32);
        const u64 p2 = (u64)__shfl_xor((long long)m2[c], 32);
        kins(p0, m0[c], m1[c], m2[c]);
        kins(p1, m0[c], m1[c], m2[c]);
        kins(p2, m0[c], m1[c], m2[c]);
    }

    // ---- Entropy wave reduction; lane 0 writes ent[b] ----
    #pragma unroll
    for (int off = 32; off > 0; off >>= 1)
        esum += __shfl_down(esum, off);
    if (l == 0)
        out_ent[b] = esum * (1.0f / Fn);

    // ---- Per-lane order selection for its 4 columns -> bitmasks ----
    u64 q[4];
    #pragma unroll
    for (int c = 0; c < 4; ++c) {
        const float v0 = __uint_as_float((unsigned)(m0[c] >> 6));
        const float v1 = __uint_as_float((unsigned)(m1[c] >> 6));
        const float v2 = __uint_as_float((unsigned)(m2[c] >> 6));
        const int   i0 = 63 ^ (int)(m0[c] & 63);
        const int   i1 = 63 ^ (int)(m1[c] & 63);
        const int   i2 = 63 ^ (int)(m2[c] & 63);
        // Match numpy f32 evaluation order; no FMA contraction.
        const float p3  = __fmul_rn(__fmul_rn(v0, v0), v0);
        const float p2_ = __fmul_rn(__fmul_rn(__fmul_rn(3.0f, v1), v2), __fadd_rn(v1, v2));
        const float p1_ = __fmul_rn(__fmul_rn(__fmul_rn(6.0f, v0), v1), v2);
        const bool c3 = (p3  > p2_) && (p3  > p1_);
        const bool c2 = (p2_ >= p3) && (p2_ > p1_);
        const int  j1 = c3 ? i0 : i1;
        const int  j2 = (c3 || c2) ? i0 : i2;
        q[c] = (1ull << i0) | (1ull << j1) | (1ull << j2);
    }

    // ---- adj = pred-bit & mask-bit, pure NT store burst ----
    f32x4* a4 = (f32x4*)(out_adj + (size_t)b * NPB);
    #pragma unroll 8
    for (int i = 0; i < 32; ++i) {
        const int idx = l + 64 * i;
        const int r   = rbase + 2 * i;
        f32x4 a;
        a.x = (((pr[0] >> i) & 1u) && ((q[0] >> r) & 1ull)) ? 1.0f : 0.0f;
        a.y = (((pr[1] >> i) & 1u) && ((q[1] >> r) & 1ull)) ? 1.0f : 0.0f;
        a.z = (((pr[2] >> i) & 1u) && ((q[2] >> r) & 1ull)) ? 1.0f : 0.0f;
        a.w = (((pr[3] >> i) & 1u) && ((q[3] >> r) & 1ull)) ? 1.0f : 0.0f;
        __builtin_nontemporal_store(a, &a4[idx]);
    }
}

extern "C" void kernel_launch(void* const* d_in, const int* in_sizes, int n_in,
                              void* d_out, int out_size, void* d_ws, size_t ws_size,
                              hipStream_t stream) {
    const float* softmax = (const float*)d_in[0];
    // d_in[1] (log_probs) unused: ent computed as -p*log(p) (error < 1e-6 abs).

    float* out     = (float*)d_out;
    float* out_sm  = out;                              // [B,V,F] f32
    float* out_adj = out + (size_t)Bn * NPB;           // [B,V,F] as f32 0/1
    float* out_ent = out + 2 * (size_t)Bn * NPB;       // [B]

    adj_generator_kernel<<<Bn / 4, 256, 0, stream>>>(softmax, out_sm, out_adj, out_ent);
}

// Round 8
// 75.953 us; speedup vs baseline: 1.0476x; 1.0476x over previous
//
#include <hip/hip_runtime.h>

// Problem constants (from reference): B=4096, V=64 (variables), F=128 (factors), HO=3
constexpr int Bn  = 4096;
constexpr int Vn  = 64;
constexpr int Fn  = 128;
constexpr int NPB = Vn * Fn;    // 8192 elements per batch slice
constexpr int GRID = Bn / 2;    // each block pipelines 2 batches: b and b+GRID

typedef float f32x4 __attribute__((ext_vector_type(4)));
typedef unsigned long long u64;

// Branchless insert of key k into descending triple (m0 >= m1 >= m2).
// Key = (float_bits << 6) | (63 ^ row): value desc, row asc on ties (= stable
// top_k; keys are unique so merges in any order give the global top-3).
__device__ __forceinline__ void kins(u64 k, u64& m0, u64& m1, u64& m2) {
    const u64 a = m0 > k ? m0 : k;
    const u64 b = m0 > k ? k  : m0;
    m0 = a;
    const u64 c = m1 > b ? m1 : b;
    const u64 d = m1 > b ? b  : m1;
    m1 = c;
    m2 = m2 > d ? m2 : d;
}

// Streaming scan of one batch slice: NT load + NT copy + entropy + pred bits +
// branchless per-column top-3. If STORE_PREV, also interleaves the adj stores
// of the PREVIOUS batch (masks q_prev, pred bits pred_prev) into the same loop
// so the memory system sees a steady 1-read : 2-write mix.
template<bool STORE_PREV>
__device__ __forceinline__ void scan_batch(const f32x4* __restrict__ s4,
                                           f32x4* __restrict__ o4,
                                           f32x4* __restrict__ a4_prev,
                                           unsigned pred_prev,
                                           const u64* q_prev,
                                           const int t, const int rbase,
                                           unsigned& pred, float& esum,
                                           u64* m0, u64* m1, u64* m2) {
    #pragma unroll
    for (int i = 0; i < 8; ++i) {
        const int idx = t + i * 256;
        const f32x4 v = __builtin_nontemporal_load(&s4[idx]);
        __builtin_nontemporal_store(v, &o4[idx]);      // softmax pass-through
        if constexpr (STORE_PREV) {
            const int r = rbase + 8 * i;
            f32x4 a;
            a.x = (((pred_prev >> (4*i    )) & 1u) && ((q_prev[0] >> r) & 1ull)) ? 1.0f : 0.0f;
            a.y = (((pred_prev >> (4*i + 1)) & 1u) && ((q_prev[1] >> r) & 1ull)) ? 1.0f : 0.0f;
            a.z = (((pred_prev >> (4*i + 2)) & 1u) && ((q_prev[2] >> r) & 1ull)) ? 1.0f : 0.0f;
            a.w = (((pred_prev >> (4*i + 3)) & 1u) && ((q_prev[3] >> r) & 1ull)) ? 1.0f : 0.0f;
            __builtin_nontemporal_store(a, &a4_prev[idx]);
        }
        esum -= v.x * __logf(v.x) + v.y * __logf(v.y)
              + v.z * __logf(v.z) + v.w * __logf(v.w);
        pred |= ((v.x > 0.01f ? 1u : 0u) << (4*i    ))
              | ((v.y > 0.01f ? 1u : 0u) << (4*i + 1))
              | ((v.z > 0.01f ? 1u : 0u) << (4*i + 2))
              | ((v.w > 0.01f ? 1u : 0u) << (4*i + 3));
        const u64 rk = (u64)(63 ^ (rbase + 8 * i));
        kins(((u64)__float_as_uint(v.x) << 6) | rk, m0[0], m1[0], m2[0]);
        kins(((u64)__float_as_uint(v.y) << 6) | rk, m0[1], m1[1], m2[1]);
        kins(((u64)__float_as_uint(v.z) << 6) | rk, m0[2], m1[2], m2[2]);
        kins(((u64)__float_as_uint(v.w) << 6) | rk, m0[3], m1[3], m2[3]);
    }
}

// Pair-merge (lanes t<->t^32 share columns), 4-way wave merge through LDS,
// entropy block reduction, order selection -> per-factor bitmask in topm.
__device__ __forceinline__ void merge_finalize(const int t, const int wv, const int col0,
                                               u64* m0, u64* m1, u64* m2, float esum,
                                               u64 (*part)[4][Fn], u64* topm,
                                               float* wsum, float* ent_out) {
    #pragma unroll
    for (int c = 0; c < 4; ++c) {
        const u64 p0 = (u64)__shfl_xor((long long)m0[c], 32);
        const u64 p1 = (u64)__shfl_xor((long long)m1[c], 32);
        const u64 p2 = (u64)__shfl_xor((long long)m2[c], 32);
        kins(p0, m0[c], m1[c], m2[c]);
        kins(p1, m0[c], m1[c], m2[c]);
        kins(p2, m0[c], m1[c], m2[c]);
    }
    if ((t & 32) == 0) {
        #pragma unroll
        for (int c = 0; c < 4; ++c) {
            part[0][wv][col0 + c] = m0[c];
            part[1][wv][col0 + c] = m1[c];
            part[2][wv][col0 + c] = m2[c];
        }
    }
    #pragma unroll
    for (int off = 32; off > 0; off >>= 1)
        esum += __shfl_down(esum, off);
    if ((t & 63) == 0) wsum[wv] = esum;

    __syncthreads();

    if (t == 0)
        *ent_out = (wsum[0] + wsum[1] + wsum[2] + wsum[3]) * (1.0f / Fn);

    if (t < Fn) {
        u64 k0 = part[0][0][t], k1 = part[1][0][t], k2 = part[2][0][t];
        #pragma unroll
        for (int w = 1; w < 4; ++w) {
            kins(part[0][w][t], k0, k1, k2);
            kins(part[1][w][t], k0, k1, k2);
            kins(part[2][w][t], k0, k1, k2);
        }
        const float v0 = __uint_as_float((unsigned)(k0 >> 6));
        const float v1 = __uint_as_float((unsigned)(k1 >> 6));
        const float v2 = __uint_as_float((unsigned)(k2 >> 6));
        const int   i0 = 63 ^ (int)(k0 & 63);
        const int   i1 = 63 ^ (int)(k1 & 63);
        const int   i2 = 63 ^ (int)(k2 & 63);
        // Match numpy f32 evaluation order; no FMA contraction.
        const float p3  = __fmul_rn(__fmul_rn(v0, v0), v0);
        const float p2_ = __fmul_rn(__fmul_rn(__fmul_rn(3.0f, v1), v2), __fadd_rn(v1, v2));
        const float p1_ = __fmul_rn(__fmul_rn(__fmul_rn(6.0f, v0), v1), v2);
        const bool c3 = (p3  > p2_) && (p3  > p1_);
        const bool c2 = (p2_ >= p3) && (p2_ > p1_);
        const int  j1 = c3 ? i0 : i1;
        const int  j2 = (c3 || c2) ? i0 : i2;
        topm[t] = (1ull << i0) | (1ull << j1) | (1ull << j2);
    }
    __syncthreads();
}

// Block pipelines two batches b0 and b1=b0+GRID: while streaming/scanning b1,
// the adj stores of b0 are interleaved into the same loop (steady 1R:2W mix).
// Only b1's adj tail is exposed, hidden by 2x block oversubscription.
__global__ __launch_bounds__(256)
void adj_generator_kernel(const float* __restrict__ sm_g,
                          float* __restrict__ out_sm,
                          float* __restrict__ out_adj,
                          float* __restrict__ out_ent) {
    const int t  = threadIdx.x;
    const int b0 = blockIdx.x;
    const int b1 = blockIdx.x + GRID;

    __shared__ u64   part[3][4][Fn];           // per-wave partial top-3 keys (12 KiB)
    __shared__ u64   topm[2][Fn];              // per-factor bitmasks for b0, b1 (2 KiB)
    __shared__ float wsum[4];

    const int wv    = t >> 6;
    const int col0  = (4 * t) & (Fn - 1);
    const int rbase = t >> 5;

    const f32x4* s4_0 = (const f32x4*)(sm_g   + (size_t)b0 * NPB);
    f32x4*       o4_0 = (f32x4*)(out_sm + (size_t)b0 * NPB);
    const f32x4* s4_1 = (const f32x4*)(sm_g   + (size_t)b1 * NPB);
    f32x4*       o4_1 = (f32x4*)(out_sm + (size_t)b1 * NPB);
    f32x4*       a4_0 = (f32x4*)(out_adj + (size_t)b0 * NPB);
    f32x4*       a4_1 = (f32x4*)(out_adj + (size_t)b1 * NPB);

    // ---- Batch b0: scan ----
    u64 m0[4], m1[4], m2[4];
    #pragma unroll
    for (int c = 0; c < 4; ++c) { m0[c] = 0; m1[c] = 0; m2[c] = 0; }
    unsigned pred0 = 0;
    float es0 = 0.0f;
    scan_batch<false>(s4_0, o4_0, nullptr, 0u, nullptr, t, rbase, pred0, es0, m0, m1, m2);
    merge_finalize(t, wv, col0, m0, m1, m2, es0, part, topm[0], wsum, out_ent + b0);

    // ---- Pick up b0 masks, then scan b1 with b0's adj stores interleaved ----
    u64 q0[4];
    #pragma unroll
    for (int c = 0; c < 4; ++c) q0[c] = topm[0][col0 + c];

    #pragma unroll
    for (int c = 0; c < 4; ++c) { m0[c] = 0; m1[c] = 0; m2[c] = 0; }
    unsigned pred1 = 0;
    float es1 = 0.0f;
    scan_batch<true>(s4_1, o4_1, a4_0, pred0, q0, t, rbase, pred1, es1, m0, m1, m2);
    merge_finalize(t, wv, col0, m0, m1, m2, es1, part, topm[1], wsum, out_ent + b1);

    // ---- b1 adj tail ----
    u64 q1[4];
    #pragma unroll
    for (int c = 0; c < 4; ++c) q1[c] = topm[1][col0 + c];
    #pragma unroll
    for (int i = 0; i < 8; ++i) {
        const int idx = t + i * 256;
        const int r   = rbase + 8 * i;
        f32x4 a;
        a.x = (((pred1 >> (4*i    )) & 1u) && ((q1[0] >> r) & 1ull)) ? 1.0f : 0.0f;
        a.y = (((pred1 >> (4*i + 1)) & 1u) && ((q1[1] >> r) & 1ull)) ? 1.0f : 0.0f;
        a.z = (((pred1 >> (4*i + 2)) & 1u) && ((q1[2] >> r) & 1ull)) ? 1.0f : 0.0f;
        a.w = (((pred1 >> (4*i + 3)) & 1u) && ((q1[3] >> r) & 1ull)) ? 1.0f : 0.0f;
        __builtin_nontemporal_store(a, &a4_1[idx]);
    }
}

extern "C" void kernel_launch(void* const* d_in, const int* in_sizes, int n_in,
                              void* d_out, int out_size, void* d_ws, size_t ws_size,
                              hipStream_t stream) {
    const float* softmax = (const float*)d_in[0];
    // d_in[1] (log_probs) unused: ent computed as -p*log(p) (error < 1e-6 abs).

    float* out     = (float*)d_out;
    float* out_sm  = out;                              // [B,V,F] f32
    float* out_adj = out + (size_t)Bn * NPB;           // [B,V,F] as f32 0/1
    float* out_ent = out + 2 * (size_t)Bn * NPB;       // [B]

    adj_generator_kernel<<<GRID, 256, 0, stream>>>(softmax, out_sm, out_adj, out_ent);
}

// Round 9
// 63.919 us; speedup vs baseline: 1.2448x; 1.1883x over previous
//
#include <hip/hip_runtime.h>

// Problem constants (from reference): B=4096, V=64 (variables), F=128 (factors), HO=3
constexpr int Bn  = 4096;
constexpr int Vn  = 64;
constexpr int Fn  = 128;
constexpr int NPB = Vn * Fn;   // 8192 elements per batch slice

typedef float f32x4 __attribute__((ext_vector_type(4)));
typedef unsigned long long u64;

typedef const float __attribute__((address_space(1)))* gas1;
typedef float __attribute__((address_space(3)))*       las3;

// Counted vmcnt wait (never 0 in steady state) + compiler memory fence.
#define WAITVM(n) asm volatile("s_waitcnt vmcnt(" #n ")" ::: "memory")
#define CFENCE()  asm volatile("" ::: "memory")

// Branchless insert of key k into descending triple (m0 >= m1 >= m2).
// Key = (float_bits << 6) | (63 ^ row): value desc, row asc on ties (= stable
// top_k; keys are unique so merges in any order give the global top-3).
__device__ __forceinline__ void kins(u64 k, u64& m0, u64& m1, u64& m2) {
    const u64 a = m0 > k ? m0 : k;
    const u64 b = m0 > k ? k  : m0;
    m0 = a;
    const u64 c = m1 > b ? m1 : b;
    const u64 d = m1 > b ? b  : m1;
    m1 = c;
    m2 = m2 > d ? m2 : d;
}

// ONE WAVE PER BATCH (R7 compute, proven exact). Lane l, global iter I reads
// f32x4 #(l + 64*I): col = (4l)&127 constant per lane, row = (l>>5) + 2*I.
// Input is staged via async global_load_lds into per-wave double-buffered
// 8 KiB super-chunks: the read stream's in-flight depth is no longer bound
// by VGPRs (8 KiB/wave in flight vs ~2.6 KB/CU required). Zero barriers.
__global__ __launch_bounds__(256)
void adj_generator_kernel(const float* __restrict__ sm_g,
                          float* __restrict__ out_sm,
                          float* __restrict__ out_adj,
                          float* __restrict__ out_ent) {
    __shared__ f32x4 stage[4][2][512];     // [wave][buf][8 KiB] = 64 KiB/block

    const int wv = threadIdx.x >> 6;       // wave within block
    const int l  = threadIdx.x & 63;       // lane
    const int b  = blockIdx.x * 4 + wv;    // batch handled by this wave

    const float* gsrc = sm_g + (size_t)b * NPB;
    f32x4* o4 = (f32x4*)(out_sm  + (size_t)b * NPB);
    f32x4* a4 = (f32x4*)(out_adj + (size_t)b * NPB);

    u64 m0[4], m1[4], m2[4];
    #pragma unroll
    for (int c = 0; c < 4; ++c) { m0[c] = 0; m1[c] = 0; m2[c] = 0; }
    unsigned pr[4] = {0u, 0u, 0u, 0u};     // (x > 0.01) bit per global iter, per col
    float esum = 0.0f;                     // -sum p*log2(p), scaled by ln2 at the end
    const int rbase = l >> 5;              // 0 (even rows) or 1 (odd rows)

    // Issue one 8 KiB super-chunk stage: 8 x global_load_lds (16 B/lane each).
    // LDS dest is wave-uniform base + lane*16 (linear mirror of the slice).
    auto stage_sc = [&](int buf, int sc) {
        #pragma unroll
        for (int c = 0; c < 8; ++c) {
            const float* gp = gsrc + sc * 2048 + c * 256 + l * 4;
            __builtin_amdgcn_global_load_lds((gas1)gp,
                                             (las3)&stage[wv][buf][c * 64],
                                             16, 0, 0);
        }
        CFENCE();
    };

    // Consume one staged super-chunk: 8 x (ds_read_b128 -> entropy, pred,
    // branchless top-3, NT softmax pass-through store).
    auto process = [&](int buf, int sc) {
        #pragma unroll
        for (int i = 0; i < 8; ++i) {
            const int I = sc * 8 + i;                  // global iter 0..31
            const f32x4 v = stage[wv][buf][i * 64 + l];
            __builtin_nontemporal_store(v, &o4[l + 64 * I]);
            esum -= v.x * __log2f(v.x) + v.y * __log2f(v.y)
                  + v.z * __log2f(v.z) + v.w * __log2f(v.w);
            pr[0] |= (v.x > 0.01f ? 1u : 0u) << I;
            pr[1] |= (v.y > 0.01f ? 1u : 0u) << I;
            pr[2] |= (v.z > 0.01f ? 1u : 0u) << I;
            pr[3] |= (v.w > 0.01f ? 1u : 0u) << I;
            const u64 rk = (u64)(63 ^ (rbase + 2 * I));
            kins(((u64)__float_as_uint(v.x) << 6) | rk, m0[0], m1[0], m2[0]);
            kins(((u64)__float_as_uint(v.y) << 6) | rk, m0[1], m1[1], m2[1]);
            kins(((u64)__float_as_uint(v.z) << 6) | rk, m0[2], m1[2], m2[2]);
            kins(((u64)__float_as_uint(v.w) << 6) | rk, m0[3], m1[3], m2[3]);
        }
        CFENCE();
    };

    // vmcnt accounting (ops younger than the stage being waited on):
    //   sc0: stage(sc1)=8                      -> WAITVM(8)
    //   sc1: stores(sc0)=8 + stage(sc2)=8      -> WAITVM(16)
    //   sc2: stores(sc1)=8 + stage(sc3)=8      -> WAITVM(16)
    //   sc3: stores(sc2)=8                     -> WAITVM(8)
    stage_sc(0, 0);
    stage_sc(1, 1); WAITVM(8);  process(0, 0);
    stage_sc(0, 2); WAITVM(16); process(1, 1);
    stage_sc(1, 3); WAITVM(16); process(0, 2);
                    WAITVM(8);  process(1, 3);

    // ---- Pair-merge: lane l <-> l^32 (same cols, complementary rows) ----
    #pragma unroll
    for (int c = 0; c < 4; ++c) {
        const u64 p0 = (u64)__shfl_xor((long long)m0[c], 32);
        const u64 p1 = (u64)__shfl_xor((long long)m1[c], 32);
        const u64 p2 = (u64)__shfl_xor((long long)m2[c], 32);
        kins(p0, m0[c], m1[c], m2[c]);
        kins(p1, m0[c], m1[c], m2[c]);
        kins(p2, m0[c], m1[c], m2[c]);
    }

    // ---- Entropy wave reduction; lane 0 writes ent[b] (log2 -> ln scale) ----
    #pragma unroll
    for (int off = 32; off > 0; off >>= 1)
        esum += __shfl_down(esum, off);
    if (l == 0)
        out_ent[b] = esum * (0.69314718055994530942f / 128.0f);

    // ---- Per-lane order selection for its 4 columns -> bitmasks ----
    u64 q[4];
    #pragma unroll
    for (int c = 0; c < 4; ++c) {
        const float v0 = __uint_as_float((unsigned)(m0[c] >> 6));
        const float v1 = __uint_as_float((unsigned)(m1[c] >> 6));
        const float v2 = __uint_as_float((unsigned)(m2[c] >> 6));
        const int   i0 = 63 ^ (int)(m0[c] & 63);
        const int   i1 = 63 ^ (int)(m1[c] & 63);
        const int   i2 = 63 ^ (int)(m2[c] & 63);
        // Match numpy f32 evaluation order; no FMA contraction.
        const float p3  = __fmul_rn(__fmul_rn(v0, v0), v0);
        const float p2_ = __fmul_rn(__fmul_rn(__fmul_rn(3.0f, v1), v2), __fadd_rn(v1, v2));
        const float p1_ = __fmul_rn(__fmul_rn(__fmul_rn(6.0f, v0), v1), v2);
        const bool c3 = (p3  > p2_) && (p3  > p1_);
        const bool c2 = (p2_ >= p3) && (p2_ > p1_);
        const int  j1 = c3 ? i0 : i1;
        const int  j2 = (c3 || c2) ? i0 : i2;
        q[c] = (1ull << i0) | (1ull << j1) | (1ull << j2);
    }

    // ---- adj = pred-bit & mask-bit, pure NT store burst (fire-and-forget,
    //      hidden behind the next resident blocks' load streams) ----
    #pragma unroll 8
    for (int I = 0; I < 32; ++I) {
        const int r = rbase + 2 * I;
        f32x4 a;
        a.x = (((pr[0] >> I) & 1u) && ((q[0] >> r) & 1ull)) ? 1.0f : 0.0f;
        a.y = (((pr[1] >> I) & 1u) && ((q[1] >> r) & 1ull)) ? 1.0f : 0.0f;
        a.z = (((pr[2] >> I) & 1u) && ((q[2] >> r) & 1ull)) ? 1.0f : 0.0f;
        a.w = (((pr[3] >> I) & 1u) && ((q[3] >> r) & 1ull)) ? 1.0f : 0.0f;
        __builtin_nontemporal_store(a, &a4[l + 64 * I]);
    }
}

extern "C" void kernel_launch(void* const* d_in, const int* in_sizes, int n_in,
                              void* d_out, int out_size, void* d_ws, size_t ws_size,
                              hipStream_t stream) {
    const float* softmax = (const float*)d_in[0];
    // d_in[1] (log_probs) unused: ent computed as -p*log(p) (error < 1e-6 abs).

    float* out     = (float*)d_out;
    float* out_sm  = out;                              // [B,V,F] f32
    float* out_adj = out + (size_t)Bn * NPB;           // [B,V,F] as f32 0/1
    float* out_ent = out + 2 * (size_t)Bn * NPB;       // [B]

    adj_generator_kernel<<<Bn / 4, 256, 0, stream>>>(softmax, out_sm, out_adj, out_ent);
}